// Round 2
// baseline (112.573 us; speedup 1.0000x reference)
//
#include <hip/hip_runtime.h>
#include <hip/hip_bf16.h>

#define SEQ 1024
#define DK 8
#define NH 12
#define BATCH 8
#define NQ 96
#define ED 768

typedef __attribute__((ext_vector_type(8))) _Float16 half8;
typedef __attribute__((ext_vector_type(2))) __fp16 fp16x2;
typedef __attribute__((ext_vector_type(4))) float floatx4;

__device__ __forceinline__ float fast_exp2(float x) {
#if __has_builtin(__builtin_amdgcn_exp2f)
    return __builtin_amdgcn_exp2f(x);
#else
    return exp2f(x);
#endif
}

// Pack two fp32 -> fp16x2 in one v_cvt_pkrtz_f16_f32, as a 32-bit word.
__device__ __forceinline__ unsigned pkh(float lo, float hi) {
    union { fp16x2 h; unsigned u; } v;
    v.h = __builtin_amdgcn_cvt_pkrtz(lo, hi);
    return v.u;
}

// gfx950 lane-pair swaps (VALU cross-lane, no DS traffic).
// permlane32_swap: a[32..63] <-> b[0..31]
__device__ __forceinline__ void pl32_swap(unsigned &a, unsigned &b) {
#if __has_builtin(__builtin_amdgcn_permlane32_swap)
    auto r = __builtin_amdgcn_permlane32_swap(a, b, false, false);
    a = r[0]; b = r[1];
#else
    asm("v_permlane32_swap_b32 %0, %1" : "+v"(a), "+v"(b));
#endif
}
// permlane16_swap: a[16..31] <-> b[0..15], a[48..63] <-> b[32..47]
__device__ __forceinline__ void pl16_swap(unsigned &a, unsigned &b) {
#if __has_builtin(__builtin_amdgcn_permlane16_swap)
    auto r = __builtin_amdgcn_permlane16_swap(a, b, false, false);
    a = r[0]; b = r[1];
#else
    asm("v_permlane16_swap_b32 %0, %1" : "+v"(a), "+v"(b));
#endif
}

// ---------------------------------------------------------------------------
// Fused quantum-attention via fp16 MFMA (R6/R7-verified addressing).
// One block = (b, h, 128-query chunk), 512 threads = 8 waves, one 16-query
// tile per wave, 1024 keys in 32-key windows.  Scores bounded => no softmax
// max/rescale.
//
// R10 (verified, -15.8us): P^T transpose via 2x permlane32_swap +
// 2x permlane16_swap (no LDS round-trip); PV B-frag column 8 = ones so the
// PV MFMA accumulates the softmax denominator for free; LDS 57->32 KB.
//
// R11: window loop unroll 4 (scheduling room so next window's DS reads
// issue under the exp chain); s_setprio(1) around the MFMA cluster
// (waves in this loop are barrier-free => phase-drifted => setprio regime).
//
// LDS:
//   qv   (1024x8 fp16, scaled by sqrt(log2e/sqrt8)) — feeds A and B of QK^T.
//   qvt2 (tiled V'): (win,q,n,j) -> win*256 + q*64 + n*8 + j, n<8 only;
//        PV B-frag is one contiguous ds_read_b128 per lane.
// ---------------------------------------------------------------------------
__global__ __launch_bounds__(512, 6) void attn_kernel(
    const float* __restrict__ x, const float* __restrict__ theta,
    _Float16* __restrict__ attn /* (BATCH*SEQ, NQ) fp16 */)
{
    __shared__ __align__(16) _Float16 qv[SEQ * DK];     // 16 KB
    __shared__ __align__(16) _Float16 qvt2[32 * 256];   // 16 KB
    __shared__ __align__(16) _Float16 zbuf[16];         // zeros (B cols 9..15, A pads)
    __shared__ __align__(16) _Float16 obuf[8];          // ones  (B col 8 = denominator)

    const int chunk = blockIdx.x;   // 0..7  (128 queries)
    const int h     = blockIdx.y;
    const int b     = blockIdx.z;
    const int tid   = threadIdx.x;

    const float SQS = 0.71419170f;  // sqrt(log2(e)/sqrt(8))

    float ct[8];
    #pragma unroll
    for (int k = 0; k < 8; ++k) ct[k] = __cosf(theta[h * DK + k]);

    if (tid < 16) zbuf[tid] = (_Float16)0.0f;
    if (tid >= 16 && tid < 24) obuf[tid - 16] = (_Float16)1.0f;

    // ---- stage q into qv (scaled) and qvt2 (tiled, unscaled, cols 0..7) ----
    #pragma unroll
    for (int it = 0; it < 2; ++it) {
        const int s = tid + it * 512;
        const float* xp = x + ((size_t)(b * SEQ + s)) * ED + h * DK;
        const float4 v0 = *(const float4*)xp;
        const float4 v1 = *(const float4*)(xp + 4);
        float q[8];
        q[0] = __cosf(v0.x) * ct[0]; q[1] = __cosf(v0.y) * ct[1];
        q[2] = __cosf(v0.z) * ct[2]; q[3] = __cosf(v0.w) * ct[3];
        q[4] = __cosf(v1.x) * ct[4]; q[5] = __cosf(v1.y) * ct[5];
        q[6] = __cosf(v1.z) * ct[6]; q[7] = __cosf(v1.w) * ct[7];
        union { half8 v; _Float16 e[8]; } row;
        #pragma unroll
        for (int k = 0; k < 8; ++k) row.e[k] = (_Float16)(q[k] * SQS);
        *(half8*)&qv[s * DK] = row.v;
        const int e0 = (s >> 5) * 256 + ((s >> 3) & 3) * 64 + (s & 7);
        #pragma unroll
        for (int k = 0; k < 8; ++k) qvt2[e0 + k * 8] = (_Float16)q[k];
    }
    __syncthreads();

    const int w    = tid >> 6;       // wave 0..7
    const int lane = tid & 63;
    const int l15  = lane & 15;
    const int qt   = lane >> 4;
    const int m0w  = chunk * 128 + w * 16;

    // Score MFMA B-frag: Q rows of my 16-query tile (quad 0 only).
    const half8 bfm = *(const half8*)((qt == 0) ? &qv[(m0w + l15) * DK] : zbuf);

    const _Float16* pa0 = (qt == 0) ? &qv[l15 * DK]        : zbuf;
    const _Float16* pa1 = (qt == 0) ? &qv[(16 + l15) * DK] : zbuf;
    const int ainc = (qt == 0) ? 32 * DK : 0;        // 32 key-rows per window

    // PV B-frag: V[key qt*8+j][dim l15]; col 8 = ones (denominator), 9..15 = 0.
    const _Float16* pv;
    int pvinc;
    if (l15 < 8)       { pv = &qvt2[qt * 64 + l15 * 8]; pvinc = 256; }
    else if (l15 == 8) { pv = obuf;                     pvinc = 0;   }
    else               { pv = zbuf;                     pvinc = 0;   }

    floatx4 acc = {0.f, 0.f, 0.f, 0.f};
    const floatx4 zc = {0.f, 0.f, 0.f, 0.f};

    #pragma unroll 4
    for (int win = 0; win < 32; ++win) {
        const half8 af0 = *(const half8*)pa0;  pa0 += ainc;
        const half8 af1 = *(const half8*)pa1;  pa1 += ainc;
        const half8 vf  = *(const half8*)pv;   pv += pvinc;

        __builtin_amdgcn_s_setprio(1);
        floatx4 d0 = __builtin_amdgcn_mfma_f32_16x16x32_f16(af0, bfm, zc, 0, 0, 0);
        floatx4 d1 = __builtin_amdgcn_mfma_f32_16x16x32_f16(af1, bfm, zc, 0, 0, 0);
        __builtin_amdgcn_s_setprio(0);

        // d0[r]: score(key qt*4+r, query l15); d1[r]: key 16+qt*4+r.
        const float e00 = fast_exp2(d0[0]), e01 = fast_exp2(d0[1]);
        const float e02 = fast_exp2(d0[2]), e03 = fast_exp2(d0[3]);
        const float e10 = fast_exp2(d1[0]), e11 = fast_exp2(d1[1]);
        const float e12 = fast_exp2(d1[2]), e13 = fast_exp2(d1[3]);

        unsigned c0 = pkh(e00, e01), c1 = pkh(e02, e03);
        unsigned c2 = pkh(e10, e11), c3 = pkh(e12, e13);
        pl32_swap(c0, c2);
        pl32_swap(c1, c3);
        pl16_swap(c0, c2);
        pl16_swap(c1, c3);
        union { half8 h; unsigned u[4]; } pa;
        pa.u[0] = c0; pa.u[1] = c1; pa.u[2] = c2; pa.u[3] = c3;

        __builtin_amdgcn_s_setprio(1);
        acc = __builtin_amdgcn_mfma_f32_16x16x32_f16(pa.h, vf, acc, 0, 0, 0);
        __builtin_amdgcn_s_setprio(0);
    }

    // acc[r] at lane l15==8 holds L(query qt*4+r) via the ones column.
    #pragma unroll
    for (int r = 0; r < 4; ++r) {
        const float lsum = __shfl(acc[r], (lane & 48) + 8);
        const float val  = acc[r] * __builtin_amdgcn_rcpf(lsum);
        if (l15 < 8) {
            const int m = m0w + qt * 4 + r;
            attn[((size_t)(b * SEQ + m)) * NQ + h * DK + l15] = (_Float16)val;
        }
    }
}

// ---------------------------------------------------------------------------
// out = attn_fp16 @ W^T via 16x16x32 fp16 MFMA.
// R11: W conversion fused — B-frags built from fp32 W with cvt_pkrtz
// (identical RTZ numerics to the old wconv kernel; W slice is L2-resident).
// ---------------------------------------------------------------------------
__global__ __launch_bounds__(256) void proj_kernel(
    const _Float16* __restrict__ attn, const float* __restrict__ W,
    float* __restrict__ out)
{
    const int tid  = threadIdx.x;
    const int w    = tid >> 6;
    const int lane = tid & 63;
    const int l15  = lane & 15;
    const int quad = lane >> 4;

    const int m0 = blockIdx.y * 64 + w * 16;
    const int n0 = blockIdx.x * 64;

    const size_t abase = ((size_t)(m0 + l15)) * NQ + quad * 8;
    half8 af0 = *(const half8*)(attn + abase);
    half8 af1 = *(const half8*)(attn + abase + 32);
    half8 af2 = *(const half8*)(attn + abase + 64);

    floatx4 acc[4];
    #pragma unroll
    for (int c = 0; c < 4; ++c) acc[c] = (floatx4){0.f, 0.f, 0.f, 0.f};

    #pragma unroll
    for (int c = 0; c < 4; ++c) {
        const float* wr = W + ((size_t)(n0 + c * 16 + l15)) * NQ + quad * 8;
        union { half8 h; unsigned u[4]; } b0, b1, b2;
        {
            const float4 wa = *(const float4*)wr;
            const float4 wb = *(const float4*)(wr + 4);
            b0.u[0] = pkh(wa.x, wa.y); b0.u[1] = pkh(wa.z, wa.w);
            b0.u[2] = pkh(wb.x, wb.y); b0.u[3] = pkh(wb.z, wb.w);
        }
        {
            const float4 wa = *(const float4*)(wr + 32);
            const float4 wb = *(const float4*)(wr + 36);
            b1.u[0] = pkh(wa.x, wa.y); b1.u[1] = pkh(wa.z, wa.w);
            b1.u[2] = pkh(wb.x, wb.y); b1.u[3] = pkh(wb.z, wb.w);
        }
        {
            const float4 wa = *(const float4*)(wr + 64);
            const float4 wb = *(const float4*)(wr + 68);
            b2.u[0] = pkh(wa.x, wa.y); b2.u[1] = pkh(wa.z, wa.w);
            b2.u[2] = pkh(wb.x, wb.y); b2.u[3] = pkh(wb.z, wb.w);
        }
        acc[c] = __builtin_amdgcn_mfma_f32_16x16x32_f16(af0, b0.h, acc[c], 0, 0, 0);
        acc[c] = __builtin_amdgcn_mfma_f32_16x16x32_f16(af1, b1.h, acc[c], 0, 0, 0);
        acc[c] = __builtin_amdgcn_mfma_f32_16x16x32_f16(af2, b2.h, acc[c], 0, 0, 0);
    }

    #pragma unroll
    for (int c = 0; c < 4; ++c)
        #pragma unroll
        for (int r = 0; r < 4; ++r)
            out[((size_t)(m0 + quad * 4 + r)) * ED + n0 + c * 16 + l15] = acc[c][r];
}

extern "C" void kernel_launch(void* const* d_in, const int* in_sizes, int n_in,
                              void* d_out, int out_size, void* d_ws, size_t ws_size,
                              hipStream_t stream) {
    const float* x     = (const float*)d_in[0];
    const float* theta = (const float*)d_in[1];
    const float* W     = (const float*)d_in[2];
    float* out = (float*)d_out;

    _Float16* attn = (_Float16*)d_ws;   // 1.5 MB

    attn_kernel<<<dim3(8, NH, BATCH), 512, 0, stream>>>(x, theta, attn);
    proj_kernel<<<dim3(ED / 64, (BATCH * SEQ) / 64), 256, 0, stream>>>(attn, W, out);
}

// Round 3
// 112.311 us; speedup vs baseline: 1.0023x; 1.0023x over previous
//
#include <hip/hip_runtime.h>
#include <hip/hip_bf16.h>

#define SEQ 1024
#define DK 8
#define NH 12
#define BATCH 8
#define NQ 96
#define ED 768

typedef __attribute__((ext_vector_type(8))) _Float16 half8;
typedef __attribute__((ext_vector_type(2))) __fp16 fp16x2;
typedef __attribute__((ext_vector_type(4))) float floatx4;

__device__ __forceinline__ float fast_exp2(float x) {
#if __has_builtin(__builtin_amdgcn_exp2f)
    return __builtin_amdgcn_exp2f(x);
#else
    return exp2f(x);
#endif
}

// Pack two fp32 -> fp16x2 in one v_cvt_pkrtz_f16_f32, as a 32-bit word.
__device__ __forceinline__ unsigned pkh(float lo, float hi) {
    union { fp16x2 h; unsigned u; } v;
    v.h = __builtin_amdgcn_cvt_pkrtz(lo, hi);
    return v.u;
}

// gfx950 lane-pair swaps (VALU cross-lane, no DS traffic).
// permlane32_swap: a[32..63] <-> b[0..31]
__device__ __forceinline__ void pl32_swap(unsigned &a, unsigned &b) {
#if __has_builtin(__builtin_amdgcn_permlane32_swap)
    auto r = __builtin_amdgcn_permlane32_swap(a, b, false, false);
    a = r[0]; b = r[1];
#else
    asm("v_permlane32_swap_b32 %0, %1" : "+v"(a), "+v"(b));
#endif
}
// permlane16_swap: a[16..31] <-> b[0..15], a[48..63] <-> b[32..47]
__device__ __forceinline__ void pl16_swap(unsigned &a, unsigned &b) {
#if __has_builtin(__builtin_amdgcn_permlane16_swap)
    auto r = __builtin_amdgcn_permlane16_swap(a, b, false, false);
    a = r[0]; b = r[1];
#else
    asm("v_permlane16_swap_b32 %0, %1" : "+v"(a), "+v"(b));
#endif
}

// ---------------------------------------------------------------------------
// Fused quantum-attention via fp16 MFMA (R6/R7-verified addressing).
// One block = (b, h, 128-query chunk), 512 threads = 8 waves, one 16-query
// tile per wave, 1024 keys in 32-key windows.  Scores bounded => no softmax
// max/rescale.
//
// R10 (verified 104.6us): P^T transpose via 2x permlane32_swap +
// 2x permlane16_swap (no LDS round-trip); PV B-frag column 8 = ones so the
// PV MFMA accumulates the softmax denominator for free; LDS 57->32 KB.
//
// R12: A/B round. R11 (+unroll4 +setprio +wconv-fusion) regressed +8us.
// This build reverts unroll4 and setprio (loop body back to verified R10,
// unroll 2, no priority toggling — m190: setprio is null/negative without
// wave role-diversity; unroll4 at the (512,6) VGPR budget risks spills)
// and KEEPS only the wconv fusion in proj.
//
// LDS:
//   qv   (1024x8 fp16, scaled by sqrt(log2e/sqrt8)) — feeds A and B of QK^T.
//   qvt2 (tiled V'): (win,q,n,j) -> win*256 + q*64 + n*8 + j, n<8 only;
//        PV B-frag is one contiguous ds_read_b128 per lane.
// ---------------------------------------------------------------------------
__global__ __launch_bounds__(512, 6) void attn_kernel(
    const float* __restrict__ x, const float* __restrict__ theta,
    _Float16* __restrict__ attn /* (BATCH*SEQ, NQ) fp16 */)
{
    __shared__ __align__(16) _Float16 qv[SEQ * DK];     // 16 KB
    __shared__ __align__(16) _Float16 qvt2[32 * 256];   // 16 KB
    __shared__ __align__(16) _Float16 zbuf[16];         // zeros (B cols 9..15, A pads)
    __shared__ __align__(16) _Float16 obuf[8];          // ones  (B col 8 = denominator)

    const int chunk = blockIdx.x;   // 0..7  (128 queries)
    const int h     = blockIdx.y;
    const int b     = blockIdx.z;
    const int tid   = threadIdx.x;

    const float SQS = 0.71419170f;  // sqrt(log2(e)/sqrt(8))

    float ct[8];
    #pragma unroll
    for (int k = 0; k < 8; ++k) ct[k] = __cosf(theta[h * DK + k]);

    if (tid < 16) zbuf[tid] = (_Float16)0.0f;
    if (tid >= 16 && tid < 24) obuf[tid - 16] = (_Float16)1.0f;

    // ---- stage q into qv (scaled) and qvt2 (tiled, unscaled, cols 0..7) ----
    #pragma unroll
    for (int it = 0; it < 2; ++it) {
        const int s = tid + it * 512;
        const float* xp = x + ((size_t)(b * SEQ + s)) * ED + h * DK;
        const float4 v0 = *(const float4*)xp;
        const float4 v1 = *(const float4*)(xp + 4);
        float q[8];
        q[0] = __cosf(v0.x) * ct[0]; q[1] = __cosf(v0.y) * ct[1];
        q[2] = __cosf(v0.z) * ct[2]; q[3] = __cosf(v0.w) * ct[3];
        q[4] = __cosf(v1.x) * ct[4]; q[5] = __cosf(v1.y) * ct[5];
        q[6] = __cosf(v1.z) * ct[6]; q[7] = __cosf(v1.w) * ct[7];
        union { half8 v; _Float16 e[8]; } row;
        #pragma unroll
        for (int k = 0; k < 8; ++k) row.e[k] = (_Float16)(q[k] * SQS);
        *(half8*)&qv[s * DK] = row.v;
        const int e0 = (s >> 5) * 256 + ((s >> 3) & 3) * 64 + (s & 7);
        #pragma unroll
        for (int k = 0; k < 8; ++k) qvt2[e0 + k * 8] = (_Float16)q[k];
    }
    __syncthreads();

    const int w    = tid >> 6;       // wave 0..7
    const int lane = tid & 63;
    const int l15  = lane & 15;
    const int qt   = lane >> 4;
    const int m0w  = chunk * 128 + w * 16;

    // Score MFMA B-frag: Q rows of my 16-query tile (quad 0 only).
    const half8 bfm = *(const half8*)((qt == 0) ? &qv[(m0w + l15) * DK] : zbuf);

    const _Float16* pa0 = (qt == 0) ? &qv[l15 * DK]        : zbuf;
    const _Float16* pa1 = (qt == 0) ? &qv[(16 + l15) * DK] : zbuf;
    const int ainc = (qt == 0) ? 32 * DK : 0;        // 32 key-rows per window

    // PV B-frag: V[key qt*8+j][dim l15]; col 8 = ones (denominator), 9..15 = 0.
    const _Float16* pv;
    int pvinc;
    if (l15 < 8)       { pv = &qvt2[qt * 64 + l15 * 8]; pvinc = 256; }
    else if (l15 == 8) { pv = obuf;                     pvinc = 0;   }
    else               { pv = zbuf;                     pvinc = 0;   }

    floatx4 acc = {0.f, 0.f, 0.f, 0.f};
    const floatx4 zc = {0.f, 0.f, 0.f, 0.f};

    #pragma unroll 2
    for (int win = 0; win < 32; ++win) {
        const half8 af0 = *(const half8*)pa0;  pa0 += ainc;
        const half8 af1 = *(const half8*)pa1;  pa1 += ainc;
        const half8 vf  = *(const half8*)pv;   pv += pvinc;

        floatx4 d0 = __builtin_amdgcn_mfma_f32_16x16x32_f16(af0, bfm, zc, 0, 0, 0);
        floatx4 d1 = __builtin_amdgcn_mfma_f32_16x16x32_f16(af1, bfm, zc, 0, 0, 0);

        // d0[r]: score(key qt*4+r, query l15); d1[r]: key 16+qt*4+r.
        const float e00 = fast_exp2(d0[0]), e01 = fast_exp2(d0[1]);
        const float e02 = fast_exp2(d0[2]), e03 = fast_exp2(d0[3]);
        const float e10 = fast_exp2(d1[0]), e11 = fast_exp2(d1[1]);
        const float e12 = fast_exp2(d1[2]), e13 = fast_exp2(d1[3]);

        unsigned c0 = pkh(e00, e01), c1 = pkh(e02, e03);
        unsigned c2 = pkh(e10, e11), c3 = pkh(e12, e13);
        pl32_swap(c0, c2);
        pl32_swap(c1, c3);
        pl16_swap(c0, c2);
        pl16_swap(c1, c3);
        union { half8 h; unsigned u[4]; } pa;
        pa.u[0] = c0; pa.u[1] = c1; pa.u[2] = c2; pa.u[3] = c3;

        acc = __builtin_amdgcn_mfma_f32_16x16x32_f16(pa.h, vf, acc, 0, 0, 0);
    }

    // acc[r] at lane l15==8 holds L(query qt*4+r) via the ones column.
    #pragma unroll
    for (int r = 0; r < 4; ++r) {
        const float lsum = __shfl(acc[r], (lane & 48) + 8);
        const float val  = acc[r] * __builtin_amdgcn_rcpf(lsum);
        if (l15 < 8) {
            const int m = m0w + qt * 4 + r;
            attn[((size_t)(b * SEQ + m)) * NQ + h * DK + l15] = (_Float16)val;
        }
    }
}

// ---------------------------------------------------------------------------
// out = attn_fp16 @ W^T via 16x16x32 fp16 MFMA.
// W conversion fused — B-frags built from fp32 W with cvt_pkrtz
// (identical RTZ numerics to the old wconv kernel; W slice is L2-resident).
// ---------------------------------------------------------------------------
__global__ __launch_bounds__(256) void proj_kernel(
    const _Float16* __restrict__ attn, const float* __restrict__ W,
    float* __restrict__ out)
{
    const int tid  = threadIdx.x;
    const int w    = tid >> 6;
    const int lane = tid & 63;
    const int l15  = lane & 15;
    const int quad = lane >> 4;

    const int m0 = blockIdx.y * 64 + w * 16;
    const int n0 = blockIdx.x * 64;

    const size_t abase = ((size_t)(m0 + l15)) * NQ + quad * 8;
    half8 af0 = *(const half8*)(attn + abase);
    half8 af1 = *(const half8*)(attn + abase + 32);
    half8 af2 = *(const half8*)(attn + abase + 64);

    floatx4 acc[4];
    #pragma unroll
    for (int c = 0; c < 4; ++c) acc[c] = (floatx4){0.f, 0.f, 0.f, 0.f};

    #pragma unroll
    for (int c = 0; c < 4; ++c) {
        const float* wr = W + ((size_t)(n0 + c * 16 + l15)) * NQ + quad * 8;
        union { half8 h; unsigned u[4]; } b0, b1, b2;
        {
            const float4 wa = *(const float4*)wr;
            const float4 wb = *(const float4*)(wr + 4);
            b0.u[0] = pkh(wa.x, wa.y); b0.u[1] = pkh(wa.z, wa.w);
            b0.u[2] = pkh(wb.x, wb.y); b0.u[3] = pkh(wb.z, wb.w);
        }
        {
            const float4 wa = *(const float4*)(wr + 32);
            const float4 wb = *(const float4*)(wr + 36);
            b1.u[0] = pkh(wa.x, wa.y); b1.u[1] = pkh(wa.z, wa.w);
            b1.u[2] = pkh(wb.x, wb.y); b1.u[3] = pkh(wb.z, wb.w);
        }
        {
            const float4 wa = *(const float4*)(wr + 64);
            const float4 wb = *(const float4*)(wr + 68);
            b2.u[0] = pkh(wa.x, wa.y); b2.u[1] = pkh(wa.z, wa.w);
            b2.u[2] = pkh(wb.x, wb.y); b2.u[3] = pkh(wb.z, wb.w);
        }
        acc[c] = __builtin_amdgcn_mfma_f32_16x16x32_f16(af0, b0.h, acc[c], 0, 0, 0);
        acc[c] = __builtin_amdgcn_mfma_f32_16x16x32_f16(af1, b1.h, acc[c], 0, 0, 0);
        acc[c] = __builtin_amdgcn_mfma_f32_16x16x32_f16(af2, b2.h, acc[c], 0, 0, 0);
    }

    #pragma unroll
    for (int c = 0; c < 4; ++c)
        #pragma unroll
        for (int r = 0; r < 4; ++r)
            out[((size_t)(m0 + quad * 4 + r)) * ED + n0 + c * 16 + l15] = acc[c][r];
}

extern "C" void kernel_launch(void* const* d_in, const int* in_sizes, int n_in,
                              void* d_out, int out_size, void* d_ws, size_t ws_size,
                              hipStream_t stream) {
    const float* x     = (const float*)d_in[0];
    const float* theta = (const float*)d_in[1];
    const float* W     = (const float*)d_in[2];
    float* out = (float*)d_out;

    _Float16* attn = (_Float16*)d_ws;   // 1.5 MB

    attn_kernel<<<dim3(8, NH, BATCH), 512, 0, stream>>>(x, theta, attn);
    proj_kernel<<<dim3(ED / 64, (BATCH * SEQ) / 64), 256, 0, stream>>>(attn, W, out);
}

// Round 4
// 102.206 us; speedup vs baseline: 1.1014x; 1.0989x over previous
//
#include <hip/hip_runtime.h>
#include <hip/hip_bf16.h>

#define SEQ 1024
#define DK 8
#define NH 12
#define BATCH 8
#define NQ 96
#define ED 768

typedef __attribute__((ext_vector_type(8))) _Float16 half8;
typedef __attribute__((ext_vector_type(2))) __fp16 fp16x2;
typedef __attribute__((ext_vector_type(4))) float floatx4;

__device__ __forceinline__ float fast_exp2(float x) {
#if __has_builtin(__builtin_amdgcn_exp2f)
    return __builtin_amdgcn_exp2f(x);
#else
    return exp2f(x);
#endif
}

// Pack two fp32 -> fp16x2 in one v_cvt_pkrtz_f16_f32, as a 32-bit word.
__device__ __forceinline__ unsigned pkh(float lo, float hi) {
    union { fp16x2 h; unsigned u; } v;
    v.h = __builtin_amdgcn_cvt_pkrtz(lo, hi);
    return v.u;
}

// gfx950 lane-pair swaps (VALU cross-lane, no DS traffic).
// permlane32_swap: a[32..63] <-> b[0..31]
__device__ __forceinline__ void pl32_swap(unsigned &a, unsigned &b) {
#if __has_builtin(__builtin_amdgcn_permlane32_swap)
    auto r = __builtin_amdgcn_permlane32_swap(a, b, false, false);
    a = r[0]; b = r[1];
#else
    asm("v_permlane32_swap_b32 %0, %1" : "+v"(a), "+v"(b));
#endif
}
// permlane16_swap: a[16..31] <-> b[0..15], a[48..63] <-> b[32..47]
__device__ __forceinline__ void pl16_swap(unsigned &a, unsigned &b) {
#if __has_builtin(__builtin_amdgcn_permlane16_swap)
    auto r = __builtin_amdgcn_permlane16_swap(a, b, false, false);
    a = r[0]; b = r[1];
#else
    asm("v_permlane16_swap_b32 %0, %1" : "+v"(a), "+v"(b));
#endif
}

// ---------------------------------------------------------------------------
// Fused quantum-attention via fp16 MFMA (R6/R7-verified addressing).
// One block = (b, h, 128-query chunk), 512 threads = 8 waves, one 16-query
// tile per wave, 1024 keys in 32-key windows.  Scores bounded => no softmax
// max/rescale.
//
// R10 (verified 104.6us): P^T transpose via 2x permlane32_swap +
// 2x permlane16_swap (no LDS round-trip); PV B-frag column 8 = ones so the
// PV MFMA accumulates the softmax denominator for free; LDS 57->32 KB.
//
// R13: exact revert to the R10 build.  A/B matrix across R10-R12 isolated
// the wconv->proj fusion as the +7.7us regression (R12 == R11 != R10):
// fp32 W doubles proj's B-path VMEM and puts ~96 cvt_pkrtz/lane on the
// load->MFMA critical path.  Separate wconv + fp16 Wh restored.
//
// LDS:
//   qv   (1024x8 fp16, scaled by sqrt(log2e/sqrt8)) — feeds A and B of QK^T.
//   qvt2 (tiled V'): (win,q,n,j) -> win*256 + q*64 + n*8 + j, n<8 only;
//        PV B-frag is one contiguous ds_read_b128 per lane.
// ---------------------------------------------------------------------------
__global__ __launch_bounds__(512, 6) void attn_kernel(
    const float* __restrict__ x, const float* __restrict__ theta,
    _Float16* __restrict__ attn /* (BATCH*SEQ, NQ) fp16 */)
{
    __shared__ __align__(16) _Float16 qv[SEQ * DK];     // 16 KB
    __shared__ __align__(16) _Float16 qvt2[32 * 256];   // 16 KB
    __shared__ __align__(16) _Float16 zbuf[16];         // zeros (B cols 9..15, A pads)
    __shared__ __align__(16) _Float16 obuf[8];          // ones  (B col 8 = denominator)

    const int chunk = blockIdx.x;   // 0..7  (128 queries)
    const int h     = blockIdx.y;
    const int b     = blockIdx.z;
    const int tid   = threadIdx.x;

    const float SQS = 0.71419170f;  // sqrt(log2(e)/sqrt(8))

    float ct[8];
    #pragma unroll
    for (int k = 0; k < 8; ++k) ct[k] = __cosf(theta[h * DK + k]);

    if (tid < 16) zbuf[tid] = (_Float16)0.0f;
    if (tid >= 16 && tid < 24) obuf[tid - 16] = (_Float16)1.0f;

    // ---- stage q into qv (scaled) and qvt2 (tiled, unscaled, cols 0..7) ----
    #pragma unroll
    for (int it = 0; it < 2; ++it) {
        const int s = tid + it * 512;
        const float* xp = x + ((size_t)(b * SEQ + s)) * ED + h * DK;
        const float4 v0 = *(const float4*)xp;
        const float4 v1 = *(const float4*)(xp + 4);
        float q[8];
        q[0] = __cosf(v0.x) * ct[0]; q[1] = __cosf(v0.y) * ct[1];
        q[2] = __cosf(v0.z) * ct[2]; q[3] = __cosf(v0.w) * ct[3];
        q[4] = __cosf(v1.x) * ct[4]; q[5] = __cosf(v1.y) * ct[5];
        q[6] = __cosf(v1.z) * ct[6]; q[7] = __cosf(v1.w) * ct[7];
        union { half8 v; _Float16 e[8]; } row;
        #pragma unroll
        for (int k = 0; k < 8; ++k) row.e[k] = (_Float16)(q[k] * SQS);
        *(half8*)&qv[s * DK] = row.v;
        const int e0 = (s >> 5) * 256 + ((s >> 3) & 3) * 64 + (s & 7);
        #pragma unroll
        for (int k = 0; k < 8; ++k) qvt2[e0 + k * 8] = (_Float16)q[k];
    }
    __syncthreads();

    const int w    = tid >> 6;       // wave 0..7
    const int lane = tid & 63;
    const int l15  = lane & 15;
    const int qt   = lane >> 4;
    const int m0w  = chunk * 128 + w * 16;

    // Score MFMA B-frag: Q rows of my 16-query tile (quad 0 only).
    const half8 bfm = *(const half8*)((qt == 0) ? &qv[(m0w + l15) * DK] : zbuf);

    const _Float16* pa0 = (qt == 0) ? &qv[l15 * DK]        : zbuf;
    const _Float16* pa1 = (qt == 0) ? &qv[(16 + l15) * DK] : zbuf;
    const int ainc = (qt == 0) ? 32 * DK : 0;        // 32 key-rows per window

    // PV B-frag: V[key qt*8+j][dim l15]; col 8 = ones (denominator), 9..15 = 0.
    const _Float16* pv;
    int pvinc;
    if (l15 < 8)       { pv = &qvt2[qt * 64 + l15 * 8]; pvinc = 256; }
    else if (l15 == 8) { pv = obuf;                     pvinc = 0;   }
    else               { pv = zbuf;                     pvinc = 0;   }

    floatx4 acc = {0.f, 0.f, 0.f, 0.f};
    const floatx4 zc = {0.f, 0.f, 0.f, 0.f};

    #pragma unroll 2
    for (int win = 0; win < 32; ++win) {
        const half8 af0 = *(const half8*)pa0;  pa0 += ainc;
        const half8 af1 = *(const half8*)pa1;  pa1 += ainc;
        const half8 vf  = *(const half8*)pv;   pv += pvinc;

        floatx4 d0 = __builtin_amdgcn_mfma_f32_16x16x32_f16(af0, bfm, zc, 0, 0, 0);
        floatx4 d1 = __builtin_amdgcn_mfma_f32_16x16x32_f16(af1, bfm, zc, 0, 0, 0);

        // d0[r]: score(key qt*4+r, query l15); d1[r]: key 16+qt*4+r.
        const float e00 = fast_exp2(d0[0]), e01 = fast_exp2(d0[1]);
        const float e02 = fast_exp2(d0[2]), e03 = fast_exp2(d0[3]);
        const float e10 = fast_exp2(d1[0]), e11 = fast_exp2(d1[1]);
        const float e12 = fast_exp2(d1[2]), e13 = fast_exp2(d1[3]);

        unsigned c0 = pkh(e00, e01), c1 = pkh(e02, e03);
        unsigned c2 = pkh(e10, e11), c3 = pkh(e12, e13);
        pl32_swap(c0, c2);
        pl32_swap(c1, c3);
        pl16_swap(c0, c2);
        pl16_swap(c1, c3);
        union { half8 h; unsigned u[4]; } pa;
        pa.u[0] = c0; pa.u[1] = c1; pa.u[2] = c2; pa.u[3] = c3;

        acc = __builtin_amdgcn_mfma_f32_16x16x32_f16(pa.h, vf, acc, 0, 0, 0);
    }

    // acc[r] at lane l15==8 holds L(query qt*4+r) via the ones column.
    #pragma unroll
    for (int r = 0; r < 4; ++r) {
        const float lsum = __shfl(acc[r], (lane & 48) + 8);
        const float val  = acc[r] * __builtin_amdgcn_rcpf(lsum);
        if (l15 < 8) {
            const int m = m0w + qt * 4 + r;
            attn[((size_t)(b * SEQ + m)) * NQ + h * DK + l15] = (_Float16)val;
        }
    }
}

// ---------------------------------------------------------------------------
// W (768x96 fp32) -> fp16.
// ---------------------------------------------------------------------------
__global__ __launch_bounds__(256) void wconv_kernel(
    const float* __restrict__ W, _Float16* __restrict__ Wh)
{
    const int i = blockIdx.x * 256 + threadIdx.x;   // float4 index
    const float4 v = ((const float4*)W)[i];
    union { unsigned u[2]; double d; } o;
    o.u[0] = pkh(v.x, v.y);
    o.u[1] = pkh(v.z, v.w);
    ((double*)Wh)[i] = o.d;
}

// ---------------------------------------------------------------------------
// out = attn_fp16 @ Wh^T via 16x16x32 fp16 MFMA (R6/R7-verified).
// ---------------------------------------------------------------------------
__global__ __launch_bounds__(256) void proj_kernel(
    const _Float16* __restrict__ attn, const _Float16* __restrict__ Wh,
    float* __restrict__ out)
{
    const int tid  = threadIdx.x;
    const int w    = tid >> 6;
    const int lane = tid & 63;
    const int l15  = lane & 15;
    const int quad = lane >> 4;

    const int m0 = blockIdx.y * 64 + w * 16;
    const int n0 = blockIdx.x * 64;

    const size_t abase = ((size_t)(m0 + l15)) * NQ + quad * 8;
    half8 af0 = *(const half8*)(attn + abase);
    half8 af1 = *(const half8*)(attn + abase + 32);
    half8 af2 = *(const half8*)(attn + abase + 64);

    floatx4 acc[4];
    #pragma unroll
    for (int c = 0; c < 4; ++c) acc[c] = (floatx4){0.f, 0.f, 0.f, 0.f};

    #pragma unroll
    for (int c = 0; c < 4; ++c) {
        const size_t bbase = ((size_t)(n0 + c * 16 + l15)) * NQ + quad * 8;
        half8 b0 = *(const half8*)(Wh + bbase);
        half8 b1 = *(const half8*)(Wh + bbase + 32);
        half8 b2 = *(const half8*)(Wh + bbase + 64);
        acc[c] = __builtin_amdgcn_mfma_f32_16x16x32_f16(af0, b0, acc[c], 0, 0, 0);
        acc[c] = __builtin_amdgcn_mfma_f32_16x16x32_f16(af1, b1, acc[c], 0, 0, 0);
        acc[c] = __builtin_amdgcn_mfma_f32_16x16x32_f16(af2, b2, acc[c], 0, 0, 0);
    }

    #pragma unroll
    for (int c = 0; c < 4; ++c)
        #pragma unroll
        for (int r = 0; r < 4; ++r)
            out[((size_t)(m0 + quad * 4 + r)) * ED + n0 + c * 16 + l15] = acc[c][r];
}

extern "C" void kernel_launch(void* const* d_in, const int* in_sizes, int n_in,
                              void* d_out, int out_size, void* d_ws, size_t ws_size,
                              hipStream_t stream) {
    const float* x     = (const float*)d_in[0];
    const float* theta = (const float*)d_in[1];
    const float* W     = (const float*)d_in[2];
    float* out = (float*)d_out;

    _Float16* attn = (_Float16*)d_ws;                                        // 1.5 MB
    _Float16* Wh   = (_Float16*)((char*)d_ws + (size_t)BATCH * SEQ * NQ * 2);

    wconv_kernel<<<dim3(ED * NQ / 4 / 256), 256, 0, stream>>>(W, Wh);
    attn_kernel<<<dim3(8, NH, BATCH), 512, 0, stream>>>(x, theta, attn);
    proj_kernel<<<dim3(ED / 64, (BATCH * SEQ) / 64), 256, 0, stream>>>(attn, Wh, out);
}